// Round 2
// baseline (53632.977 us; speedup 1.0000x reference)
//
#include <hip/hip_runtime.h>
#include <math.h>

constexpr int kB    = 256;
constexpr int kT    = 512;
constexpr int kDIN  = 64;
constexpr int kH    = 512;
constexpr int kG3   = 3 * kH;    // 1536
constexpr int kNOUT = 128;
constexpr int kHB   = kB * kH;   // elems in one h carry buffer (131072)

__device__ __forceinline__ float sigmoidf_(float x) {
  return 1.0f / (1.0f + __expf(-x));
}

// ---------------------------------------------------------------------------
// proj GEMM: C[r, 1536] = A_row(r) @ W[1536, K]^T + bias, r = 0..256*TC-1
// Row r decomposes as (b = r>>lgTC, tl = r & (TC-1));
// A row address = A + (b*Astride + tl)*K  (Astride in rows of K floats).
// grid = (1536/64, 256*TC/64), block = 256.
// ---------------------------------------------------------------------------
template <int K>
__global__ __launch_bounds__(256)
void proj_gemm(const float* __restrict__ A, int Astride, int lgTC,
               const float* __restrict__ W, const float* __restrict__ bias,
               float* __restrict__ C) {
  constexpr int BM = 64, BN = 64, BK = 16;
  __shared__ float As[BK][BM + 4];
  __shared__ float Ws[BK][BN + 4];
  const int tid = threadIdx.x;
  const int m0  = blockIdx.y * BM;
  const int n0  = blockIdx.x * BN;
  const int tx  = tid & 15;
  const int ty  = tid >> 4;
  const int lr  = tid >> 2;        // 0..63 tile row to load
  const int lk  = (tid & 3) * 4;   // k offset within tile

  const int r  = m0 + lr;
  const int b  = r >> lgTC;
  const int tl = r - (b << lgTC);
  const float* __restrict__ arow = A + ((size_t)b * Astride + tl) * K;
  const float* __restrict__ wrow = W + (size_t)(n0 + lr) * K;

  float acc[4][4] = {};

  for (int k0 = 0; k0 < K; k0 += BK) {
    const float4 av = *(const float4*)&arow[k0 + lk];
    const float4 wv = *(const float4*)&wrow[k0 + lk];
    __syncthreads();   // protect previous compute phase before overwrite
    As[lk + 0][lr] = av.x; As[lk + 1][lr] = av.y;
    As[lk + 2][lr] = av.z; As[lk + 3][lr] = av.w;
    Ws[lk + 0][lr] = wv.x; Ws[lk + 1][lr] = wv.y;
    Ws[lk + 2][lr] = wv.z; Ws[lk + 3][lr] = wv.w;
    __syncthreads();
#pragma unroll
    for (int kk = 0; kk < BK; ++kk) {
      const float4 a4 = *(const float4*)&As[kk][ty * 4];
      const float4 b4 = *(const float4*)&Ws[kk][tx * 4];
      const float a[4] = {a4.x, a4.y, a4.z, a4.w};
      const float bb[4] = {b4.x, b4.y, b4.z, b4.w};
#pragma unroll
      for (int i = 0; i < 4; ++i)
#pragma unroll
        for (int jdx = 0; jdx < 4; ++jdx)
          acc[i][jdx] = fmaf(a[i], bb[jdx], acc[i][jdx]);
    }
  }

  const float4 bv = *(const float4*)&bias[n0 + tx * 4];
#pragma unroll
  for (int i = 0; i < 4; ++i) {
    float4 cv;
    cv.x = acc[i][0] + bv.x;
    cv.y = acc[i][1] + bv.y;
    cv.z = acc[i][2] + bv.z;
    cv.w = acc[i][3] + bv.w;
    *(float4*)&C[(size_t)(m0 + ty * 4 + i) * kG3 + n0 + tx * 4] = cv;
  }
}

// ---------------------------------------------------------------------------
// One GRU timestep. grid = 256 blocks (16 batch-tiles x 16 j-tiles), 256 thr.
// Each thread owns 2 (batch, j) outputs: 6 dot-products of length 512.
// xg: chunk [256][TC][1536] (b_ih already added). hin/hout row stride given
// in floats (per-batch). hcarry != null -> also write [256][512] carry.
// ---------------------------------------------------------------------------
__global__ __launch_bounds__(256)
void gru_step(const float* __restrict__ xg, int tl, int TC,
              const float* __restrict__ whh, const float* __restrict__ bhh,
              const float* __restrict__ hin, int hinStride,
              float* __restrict__ hout, int houtStride,
              float* __restrict__ hcarry) {
  __shared__ float hs[16][kH];   // 32 KB: h_{t-1} tile [16 batches][512]

  const int tid = threadIdx.x;
  const int bt  = blockIdx.x >> 4;   // batch tile 0..15
  const int jt  = blockIdx.x & 15;   // j tile 0..15
  const int b0  = bt * 16;
  const int jj  = tid & 31;
  const int bg  = tid >> 5;          // 0..7
  const int j   = jt * 32 + jj;      // 0..511
  const int bi0 = b0 + bg;
  const int bi1 = b0 + bg + 8;

  const float* __restrict__ wr = whh + (size_t)j * kH;
  const float* __restrict__ wz = whh + (size_t)(kH + j) * kH;
  const float* __restrict__ wn = whh + (size_t)(2 * kH + j) * kH;
  const float bhr = bhh[j];
  const float bhz = bhh[kH + j];
  const float bhn = bhh[2 * kH + j];

  // --- stage h_{t-1} tile into LDS ---
  {
    const int lr = tid >> 4;           // 0..15 loader row
    const int lc = (tid & 15) * 4;     // loader col base
    const float* src = hin + (size_t)(b0 + lr) * hinStride;
#pragma unroll
    for (int it = 0; it < 8; ++it)
      *(float4*)&hs[lr][lc + it * 64] = *(const float4*)&src[lc + it * 64];
  }
  __syncthreads();

  // --- hg = h_prev @ w_hh^T for this thread's (2 batches x 3 gates) ---
  float ar0 = 0.f, az0 = 0.f, an0 = 0.f;
  float ar1 = 0.f, az1 = 0.f, an1 = 0.f;
#pragma unroll 4
  for (int k = 0; k < kH; k += 4) {
    const float4 w_r = *(const float4*)&wr[k];
    const float4 w_z = *(const float4*)&wz[k];
    const float4 w_n = *(const float4*)&wn[k];
    const float4 h0  = *(const float4*)&hs[bg][k];
    const float4 h1  = *(const float4*)&hs[bg + 8][k];
    ar0 = fmaf(w_r.x, h0.x, ar0); ar0 = fmaf(w_r.y, h0.y, ar0);
    ar0 = fmaf(w_r.z, h0.z, ar0); ar0 = fmaf(w_r.w, h0.w, ar0);
    az0 = fmaf(w_z.x, h0.x, az0); az0 = fmaf(w_z.y, h0.y, az0);
    az0 = fmaf(w_z.z, h0.z, az0); az0 = fmaf(w_z.w, h0.w, az0);
    an0 = fmaf(w_n.x, h0.x, an0); an0 = fmaf(w_n.y, h0.y, an0);
    an0 = fmaf(w_n.z, h0.z, an0); an0 = fmaf(w_n.w, h0.w, an0);
    ar1 = fmaf(w_r.x, h1.x, ar1); ar1 = fmaf(w_r.y, h1.y, ar1);
    ar1 = fmaf(w_r.z, h1.z, ar1); ar1 = fmaf(w_r.w, h1.w, ar1);
    az1 = fmaf(w_z.x, h1.x, az1); az1 = fmaf(w_z.y, h1.y, az1);
    az1 = fmaf(w_z.z, h1.z, az1); az1 = fmaf(w_z.w, h1.w, az1);
    an1 = fmaf(w_n.x, h1.x, an1); an1 = fmaf(w_n.y, h1.y, an1);
    an1 = fmaf(w_n.z, h1.z, an1); an1 = fmaf(w_n.w, h1.w, an1);
  }

  // --- gates + state update ---
  const float* xrow0 = xg + ((size_t)bi0 * TC + tl) * kG3;
  const float* xrow1 = xg + ((size_t)bi1 * TC + tl) * kG3;
  const float hp0 = hs[bg][j];
  const float hp1 = hs[bg + 8][j];

  const float r0 = sigmoidf_(xrow0[j] + ar0 + bhr);
  const float z0 = sigmoidf_(xrow0[kH + j] + az0 + bhz);
  const float n0 = tanhf(xrow0[2 * kH + j] + r0 * (an0 + bhn));
  const float hnew0 = (1.f - z0) * n0 + z0 * hp0;

  const float r1 = sigmoidf_(xrow1[j] + ar1 + bhr);
  const float z1 = sigmoidf_(xrow1[kH + j] + az1 + bhz);
  const float n1 = tanhf(xrow1[2 * kH + j] + r1 * (an1 + bhn));
  const float hnew1 = (1.f - z1) * n1 + z1 * hp1;

  hout[(size_t)bi0 * houtStride + j] = hnew0;
  hout[(size_t)bi1 * houtStride + j] = hnew1;
  if (hcarry != nullptr) {
    hcarry[(size_t)bi0 * kH + j] = hnew0;
    hcarry[(size_t)bi1 * kH + j] = hnew1;
  }
}

// ---------------------------------------------------------------------------
// FC: out[256,128] = h_last @ w_fc^T + b_fc ; h is [256][512] carry buffer
// ---------------------------------------------------------------------------
__global__ __launch_bounds__(128)
void fc_kernel(const float* __restrict__ h, const float* __restrict__ wfc,
               const float* __restrict__ bfc, float* __restrict__ out) {
  const int b = blockIdx.x;
  const int n = threadIdx.x;
  const float* hrow = h + (size_t)b * kH;
  const float* wrow = wfc + (size_t)n * kH;
  float acc = 0.f;
#pragma unroll 4
  for (int k = 0; k < kH; k += 4) {
    const float4 hv = *(const float4*)&hrow[k];
    const float4 wv = *(const float4*)&wrow[k];
    acc = fmaf(hv.x, wv.x, acc); acc = fmaf(hv.y, wv.y, acc);
    acc = fmaf(hv.z, wv.z, acc); acc = fmaf(hv.w, wv.w, acc);
  }
  out[(size_t)b * kNOUT + n] = acc + bfc[n];
}

// ---------------------------------------------------------------------------
extern "C" void kernel_launch(void* const* d_in, const int* in_sizes, int n_in,
                              void* d_out, int out_size, void* d_ws, size_t ws_size,
                              hipStream_t stream) {
  const float* x     = (const float*)d_in[0];
  const float* w_ih0 = (const float*)d_in[1];
  const float* w_hh0 = (const float*)d_in[2];
  const float* b_ih0 = (const float*)d_in[3];
  const float* b_hh0 = (const float*)d_in[4];
  const float* w_ih1 = (const float*)d_in[5];
  const float* w_hh1 = (const float*)d_in[6];
  const float* b_ih1 = (const float*)d_in[7];
  const float* b_hh1 = (const float*)d_in[8];
  const float* w_fc  = (const float*)d_in[9];
  const float* b_fc  = (const float*)d_in[10];
  float* out = (float*)d_out;

  // Pick largest chunk TC (power of 2) whose workspace fits ws_size:
  //   xgchunk [256][TC][1536] + h1chunk [256][TC][512] + 4 carry bufs [256][512]
  int TC = 64;
  while (TC > 4 &&
         ((size_t)kB * TC * (kG3 + kH) + 4 * (size_t)kHB) * sizeof(float) > ws_size)
    TC >>= 1;
  const int lg = __builtin_ctz((unsigned)TC);
  const int nchunks = kT / TC;

  float* xgchunk = (float*)d_ws;                      // 256*TC*1536
  float* h1chunk = xgchunk + (size_t)kB * TC * kG3;   // 256*TC*512
  float* hA0     = h1chunk + (size_t)kB * TC * kH;    // layer-0 carry (zero at t=0)
  float* hA1     = hA0 + kHB;                         // layer-1 ping (zero at t=0)
  float* hB1     = hA1 + kHB;                         // layer-1 pong
  // (4th slot reserved but unused: hB1 + kHB)

  // zero-init the two h-state buffers that are read before first write
  hipMemsetAsync(hA0, 0, 2 * (size_t)kHB * sizeof(float), stream);  // hA0 + hA1

  const dim3 pgrid(kG3 / 64, (kB * TC) / 64);
  const dim3 sgrid(256);

  for (int tc = 0; tc < nchunks; ++tc) {
    // --- layer-0 input projection for this chunk: xg0 = x_chunk @ w_ih0^T + b_ih0
    proj_gemm<kDIN><<<pgrid, 256, 0, stream>>>(
        x + (size_t)tc * TC * kDIN, kT, lg, w_ih0, b_ih0, xgchunk);

    // --- layer-0 recurrence: h written into h1chunk rows; carry in hA0
    for (int tl = 0; tl < TC; ++tl) {
      const float* hin = (tl == 0) ? hA0 : (h1chunk + (size_t)(tl - 1) * kH);
      const int hinStride = (tl == 0) ? kH : TC * kH;
      float* hout = h1chunk + (size_t)tl * kH;
      float* carry = (tl == TC - 1) ? hA0 : nullptr;
      gru_step<<<sgrid, 256, 0, stream>>>(xgchunk, tl, TC, w_hh0, b_hh0,
                                          hin, hinStride, hout, TC * kH, carry);
    }

    // --- layer-1 input projection for this chunk: xg1 = h1chunk @ w_ih1^T + b_ih1
    proj_gemm<kH><<<pgrid, 256, 0, stream>>>(
        h1chunk, TC, lg, w_ih1, b_ih1, xgchunk);

    // --- layer-1 recurrence: ping-pong hA1 <-> hB1 (TC even => ends in hA1)
    for (int tl = 0; tl < TC; ++tl) {
      const float* hin = (tl % 2 == 0) ? hA1 : hB1;
      float* hout      = (tl % 2 == 0) ? hB1 : hA1;
      gru_step<<<sgrid, 256, 0, stream>>>(xgchunk, tl, TC, w_hh1, b_hh1,
                                          hin, kH, hout, kH, nullptr);
    }
  }

  // --- final FC on h2 last state (in hA1 since TC is even)
  fc_kernel<<<dim3(kB), dim3(kNOUT), 0, stream>>>(hA1, w_fc, b_fc, out);
}

// Round 3
// 34134.146 us; speedup vs baseline: 1.5712x; 1.5712x over previous
//
#include <hip/hip_runtime.h>
#include <math.h>

typedef unsigned short u16;
typedef __attribute__((ext_vector_type(8))) short s8v;   // 8 x bf16 (4 VGPRs)
typedef __attribute__((ext_vector_type(4))) float f4v;   // MFMA accumulator

constexpr int kB    = 256;
constexpr int kT    = 512;
constexpr int kDIN  = 64;
constexpr int kH    = 512;
constexpr int kG3   = 1536;
constexpr int kNOUT = 128;

__device__ __forceinline__ u16 f2bf(float f) {   // round-to-nearest-even
  union { float f; unsigned u; } v; v.f = f;
  unsigned r = (v.u + 0x7FFFu + ((v.u >> 16) & 1u)) >> 16;
  return (u16)r;
}
__device__ __forceinline__ float fsig(float x) {
  x = fminf(fmaxf(x, -30.f), 30.f);
  float e = __expf(-x);
  return __fdividef(1.f, 1.f + e);
}
__device__ __forceinline__ float ftanh(float x) {
  x = fminf(fmaxf(x, -15.f), 15.f);
  float e = __expf(-2.f * x);
  return __fdividef(1.f - e, 1.f + e);
}

// ---------------------------------------------------------------------------
// Pre-swizzle w_hh [1536][512] fp32 into MFMA B-fragment stream (bf16):
// frag f = (q*3+g)*16 + kt  (q=j-group 0..31, g=gate 0..2, kt=k-tile 0..15)
// elem lane*8+i  =  w[(g*512 + q*16 + (lane&15))*512 + kt*32 + (lane>>4)*8 + i]
// ---------------------------------------------------------------------------
__global__ void build_whh(const float* __restrict__ w, u16* __restrict__ d) {
  int idx  = blockIdx.x * 256 + threadIdx.x;     // 0..98303 = frag*64+lane
  int lane = idx & 63, f = idx >> 6;
  int kt = f & 15, qg = f >> 4, g = qg % 3, q = qg / 3;
  int row = g * 512 + q * 16 + (lane & 15);
  int k0  = kt * 32 + (lane >> 4) * 8;
  const float* src = w + (size_t)row * 512 + k0;
  u16* dst = d + (size_t)f * 512 + lane * 8;
#pragma unroll
  for (int i = 0; i < 8; i++) dst[i] = f2bf(src[i]);
}

// ---------------------------------------------------------------------------
// Shared-memory union (static LDS capped at 64 KiB)
// rec : hF fp32 [16][512] (32 KB) + plane u16 [2][16][64][8] (32 KB) = 64 KB
// gemm: As/Bs u16 [128][40] x2 = 20 KB
// ---------------------------------------------------------------------------

// ---- recurrence role: one block = 16 batches, full j, TC internal steps ----
__device__ void rec_role(int cc, int TC, const float* __restrict__ xg,
                         const u16* __restrict__ wpl, const float* __restrict__ bhh,
                         u16* __restrict__ h1p, float* __restrict__ carry,
                         char* smem) {
  float* hF  = (float*)smem;                    // [16][512]
  u16*  plane = (u16*)(smem + 16 * 512 * 4);    // [2][8192]
  const int tid  = threadIdx.x;
  const int g    = blockIdx.x & 15;
  const int b0   = g * 16;
  const int w    = tid >> 6, lane = tid & 63;
  const int q0   = w * 4;                       // this wave owns j in [64w, 64w+64)

  // per-lane b_hh for my 4 j-groups (loaded once per kernel)
  float bhr[4], bhz[4], bhn[4];
#pragma unroll
  for (int qi = 0; qi < 4; qi++) {
    int j = (q0 + qi) * 16 + (lane & 15);
    bhr[qi] = bhh[j]; bhz[qi] = bhh[512 + j]; bhn[qi] = bhh[1024 + j];
  }

  // init hF from carry
  {
    int bt = tid >> 5, col0 = (tid & 31) * 16;
    const float* src = carry + (size_t)(b0 + bt) * 512 + col0;
    float* dst = &hF[bt * 512 + col0];
#pragma unroll
    for (int i2 = 0; i2 < 16; i2 += 4)
      *(float4*)&dst[i2] = *(const float4*)&src[i2];
  }
  __syncthreads();
  // build plane[0] (A-fragment layout) from hF
#pragma unroll
  for (int e = 0; e < 2; e++) {
    int gi = tid * 2 + e;                 // 0..1023 = kt*64 + lane'
    int kt2 = gi >> 6, ln2 = gi & 63;
    int m = ln2 & 15, k0 = kt2 * 32 + (ln2 >> 4) * 8;
    u16* dp = &plane[kt2 * 512 + ln2 * 8];
    const float* sp = &hF[m * 512 + k0];
#pragma unroll
    for (int i2 = 0; i2 < 8; i2++) dp[i2] = f2bf(sp[i2]);
  }
  __syncthreads();

  for (int t = 0; t < TC; t++) {
    const u16* pl = &plane[(t & 1) * 8192];
    u16* pn = &plane[((t + 1) & 1) * 8192];

    // prefetch xg (independent of LDS): [i = 4 batches][qi = 4 j-groups] x 3 gates
    float xr[4][4], xz[4][4], xn[4][4];
#pragma unroll
    for (int i = 0; i < 4; i++) {
      int b = b0 + (lane >> 4) * 4 + i;
      const float* xp = xg + ((size_t)b * TC + t) * 1536;
#pragma unroll
      for (int qi = 0; qi < 4; qi++) {
        int j = (q0 + qi) * 16 + (lane & 15);
        xr[qi][i] = xp[j]; xz[qi][i] = xp[512 + j]; xn[qi][i] = xp[1024 + j];
      }
    }

    // A-fragments for all 16 k-tiles (reused across 12 n-tiles)
    s8v a[16];
#pragma unroll
    for (int kt2 = 0; kt2 < 16; kt2++)
      a[kt2] = *(const s8v*)&pl[kt2 * 512 + lane * 8];

    // MFMA: wave owns n-tiles (q0..q0+3) x 3 gates; B streamed coalesced from global
    f4v acc[12];
#pragma unroll
    for (int u = 0; u < 12; u++) {
      f4v cacc = {0.f, 0.f, 0.f, 0.f};
      const u16* bp = wpl + (size_t)(((q0 + u / 3) * 3 + (u % 3)) * 16) * 512 + lane * 8;
#pragma unroll
      for (int kt2 = 0; kt2 < 16; kt2++) {
        s8v bv = *(const s8v*)(bp + kt2 * 512);
        cacc = __builtin_amdgcn_mfma_f32_16x16x32_bf16(a[kt2], bv, cacc, 0, 0, 0);
      }
      acc[u] = cacc;
    }

    // epilogue: gates + state update (each lane touches only (m,j) it owns)
#pragma unroll
    for (int qi = 0; qi < 4; qi++) {
      int j = (q0 + qi) * 16 + (lane & 15);
      f4v cr = acc[qi * 3 + 0], cz = acc[qi * 3 + 1], cn = acc[qi * 3 + 2];
#pragma unroll
      for (int i = 0; i < 4; i++) {
        int m = (lane >> 4) * 4 + i;
        float hp = hF[m * 512 + j];
        float r  = fsig(xr[qi][i] + cr[i] + bhr[qi]);
        float z  = fsig(xz[qi][i] + cz[i] + bhz[qi]);
        float nn = ftanh(xn[qi][i] + r * (cn[i] + bhn[qi]));
        float hnew = (1.f - z) * nn + z * hp;
        hF[m * 512 + j] = hnew;
        u16 hb = f2bf(hnew);
        pn[(j >> 5) * 512 + (m | (((j >> 3) & 3) << 4)) * 8 + (j & 7)] = hb;
        if (h1p) h1p[((size_t)(b0 + m) * TC + t) * 512 + j] = hb;
      }
    }
    __syncthreads();
  }

  // write carry back
  {
    int bt = tid >> 5, col0 = (tid & 31) * 16;
    float* dst = carry + (size_t)(b0 + bt) * 512 + col0;
    const float* src = &hF[bt * 512 + col0];
#pragma unroll
    for (int i2 = 0; i2 < 16; i2 += 4)
      *(float4*)&dst[i2] = *(const float4*)&src[i2];
  }
}

// ---- GEMM role: C[r][1536] = A[r][K] @ W[1536][K]^T + bias (bf16 MFMA) ----
// A row r -> (b=r/TC, t=r%TC); rowptr = A + (b*Abstride + Atoff + t)*K
__device__ void gemm_role(int idx, int TC,
                          const float* __restrict__ Af, const u16* __restrict__ Ab,
                          int Abstride, int Atoff, int K,
                          const float* __restrict__ Bf, const float* __restrict__ bias,
                          float* __restrict__ C, char* smem) {
  u16* As = (u16*)smem;            // [128][40]
  u16* Bs = As + 128 * 40;         // [128][40]
  const int tid = threadIdx.x;
  const int mt = idx / 12, nt = idx % 12;
  const int m0 = mt * 128, n0 = nt * 128;
  const int w = tid >> 6, lane = tid & 63;
  const int wm = w & 1, wn = w >> 1;
  const int ra = tid >> 2, koff = (tid & 3) * 8;

  const int r = m0 + ra;
  const size_t aoff = ((size_t)(r / TC) * Abstride + Atoff + (r % TC)) * K;
  const float* arowF = Af ? Af + aoff : nullptr;
  const u16*  arowB = Ab ? Ab + aoff : nullptr;
  const float* browF = Bf + (size_t)(n0 + ra) * K;

  f4v acc[4][2];
#pragma unroll
  for (int i = 0; i < 4; i++)
#pragma unroll
    for (int jn = 0; jn < 2; jn++) acc[i][jn] = (f4v){0.f, 0.f, 0.f, 0.f};

  for (int k0 = 0; k0 < K; k0 += 32) {
    s8v av, bv;
    if (arowB) {
      av = *(const s8v*)(arowB + k0 + koff);
    } else {
      u16 tmp[8];
      const float* ap = arowF + k0 + koff;
#pragma unroll
      for (int i = 0; i < 8; i++) tmp[i] = f2bf(ap[i]);
      av = *(s8v*)tmp;
    }
    {
      u16 tmp[8];
      const float* bp = browF + k0 + koff;
#pragma unroll
      for (int i = 0; i < 8; i++) tmp[i] = f2bf(bp[i]);
      bv = *(s8v*)tmp;
    }
    __syncthreads();                         // previous compute done
    *(s8v*)&As[ra * 40 + koff] = av;
    *(s8v*)&Bs[ra * 40 + koff] = bv;
    __syncthreads();
    s8v af[4];
#pragma unroll
    for (int i = 0; i < 4; i++)
      af[i] = *(const s8v*)&As[(wm * 64 + i * 16 + (lane & 15)) * 40 + (lane >> 4) * 8];
#pragma unroll
    for (int jn = 0; jn < 2; jn++) {
      s8v bf = *(const s8v*)&Bs[(wn * 32 + jn * 16 + (lane & 15)) * 40 + (lane >> 4) * 8];
#pragma unroll
      for (int i = 0; i < 4; i++)
        acc[i][jn] = __builtin_amdgcn_mfma_f32_16x16x32_bf16(af[i], bf, acc[i][jn], 0, 0, 0);
    }
  }

#pragma unroll
  for (int jn = 0; jn < 2; jn++) {
    int n = n0 + wn * 32 + jn * 16 + (lane & 15);
    float bv2 = bias[n];
#pragma unroll
    for (int i = 0; i < 4; i++) {
      int mrow = m0 + wm * 64 + i * 16 + (lane >> 4) * 4;
#pragma unroll
      for (int reg = 0; reg < 4; reg++)
        C[(size_t)(mrow + reg) * 1536 + n] = acc[i][jn][reg] + bv2;
    }
  }
}

// ---------------------------------------------------------------------------
// mega(c): blocks [0,16) rec0(c) | [16,32) rec1(c-2) | [32,32+G) proj1(c-1)
//          | [32+G,32+2G) proj0(c+1),  G = 24*TC
// ---------------------------------------------------------------------------
__global__ __launch_bounds__(512, 2)
void mega(int c, int TC, int nc,
          float* xg0a, float* xg0b, float* xg1a, float* xg1b,
          u16* h1pa, u16* h1pb,
          const float* x, const float* wih0, const float* wih1,
          const u16* whp0, const u16* whp1,
          const float* bih0, const float* bih1,
          const float* bhh0, const float* bhh1,
          float* carry) {
  __shared__ __align__(16) char smem[65536];
  const int G = 24 * TC;
  const int bid = blockIdx.x;

  if (bid < 16) {                       // rec layer 0, chunk c
    if (c >= 0 && c < nc) {
      float* xg = (c & 1) ? xg0b : xg0a;
      u16*  h1 = (c & 1) ? h1pb : h1pa;
      rec_role(c, TC, xg, whp0, bhh0, h1, carry, smem);
    }
  } else if (bid < 32) {                // rec layer 1, chunk c-2
    int cc = c - 2;
    if (cc >= 0 && cc < nc) {
      float* xg = (cc & 1) ? xg1b : xg1a;
      rec_role(cc, TC, xg, whp1, bhh1, nullptr, carry + (size_t)kB * kH, smem);
    }
  } else if (bid < 32 + G) {            // proj1: xg1(c-1) = h1(c-1) @ wih1^T + b
    int cc = c - 1;
    if (cc >= 0 && cc < nc) {
      const u16* h1 = (cc & 1) ? h1pb : h1pa;
      float* xg = (cc & 1) ? xg1b : xg1a;
      gemm_role(bid - 32, TC, nullptr, h1, TC, 0, kH, wih1, bih1, xg, smem);
    }
  } else {                              // proj0: xg0(c+1) = x(c+1) @ wih0^T + b
    int cc = c + 1;
    if (cc >= 0 && cc < nc) {
      float* xg = (cc & 1) ? xg0b : xg0a;
      gemm_role(bid - 32 - G, TC, x, nullptr, kT, cc * TC, kDIN, wih0, bih0, xg, smem);
    }
  }
}

// ---------------------------------------------------------------------------
__global__ __launch_bounds__(128)
void fc_kernel(const float* __restrict__ h, const float* __restrict__ wfc,
               const float* __restrict__ bfc, float* __restrict__ out) {
  const int b = blockIdx.x;
  const int n = threadIdx.x;
  const float* hrow = h + (size_t)b * kH;
  const float* wrow = wfc + (size_t)n * kH;
  float acc = 0.f;
#pragma unroll 4
  for (int k = 0; k < kH; k += 4) {
    const float4 hv = *(const float4*)&hrow[k];
    const float4 wv = *(const float4*)&wrow[k];
    acc = fmaf(hv.x, wv.x, acc); acc = fmaf(hv.y, wv.y, acc);
    acc = fmaf(hv.z, wv.z, acc); acc = fmaf(hv.w, wv.w, acc);
  }
  out[(size_t)b * kNOUT + n] = acc + bfc[n];
}

// ---------------------------------------------------------------------------
extern "C" void kernel_launch(void* const* d_in, const int* in_sizes, int n_in,
                              void* d_out, int out_size, void* d_ws, size_t ws_size,
                              hipStream_t stream) {
  const float* x     = (const float*)d_in[0];
  const float* w_ih0 = (const float*)d_in[1];
  const float* w_hh0 = (const float*)d_in[2];
  const float* b_ih0 = (const float*)d_in[3];
  const float* b_hh0 = (const float*)d_in[4];
  const float* w_ih1 = (const float*)d_in[5];
  const float* w_hh1 = (const float*)d_in[6];
  const float* b_ih1 = (const float*)d_in[7];
  const float* b_hh1 = (const float*)d_in[8];
  const float* w_fc  = (const float*)d_in[9];
  const float* b_fc  = (const float*)d_in[10];
  float* out = (float*)d_out;

  // adaptive chunk size: pick largest TC (divides 512) whose buffers fit ws
  auto need = [](int tc) -> size_t {
    size_t s = 0;
    s += 4 * (size_t)kB * tc * kG3 * 4;   // xg0[2] + xg1[2] fp32
    s += 2 * (size_t)kB * tc * kH * 2;    // h1 planes [2] bf16
    s += 2 * (size_t)kG3 * kH * 2;        // whh planes bf16 x2 layers
    s += 2 * (size_t)kB * kH * 4;         // carries fp32 x2 layers
    s += 8192;                            // alignment slack
    return s;
  };
  int TC = 64;
  while (TC > 1 && need(TC) > ws_size) TC >>= 1;
  const int nc = kT / TC;

  char* p = (char*)d_ws;
  auto carve = [&](size_t bytes) {
    char* r = p;
    p += (bytes + 255) & ~(size_t)255;
    return r;
  };
  float* xg0a = (float*)carve((size_t)kB * TC * kG3 * 4);
  float* xg0b = (float*)carve((size_t)kB * TC * kG3 * 4);
  float* xg1a = (float*)carve((size_t)kB * TC * kG3 * 4);
  float* xg1b = (float*)carve((size_t)kB * TC * kG3 * 4);
  u16* h1pa   = (u16*)carve((size_t)kB * TC * kH * 2);
  u16* h1pb   = (u16*)carve((size_t)kB * TC * kH * 2);
  u16* whp0   = (u16*)carve((size_t)kG3 * kH * 2);
  u16* whp1   = (u16*)carve((size_t)kG3 * kH * 2);
  float* carry = (float*)carve(2 * (size_t)kB * kH * 4);

  // prologue: weight swizzle + zero carries
  build_whh<<<384, 256, 0, stream>>>(w_hh0, whp0);
  build_whh<<<384, 256, 0, stream>>>(w_hh1, whp1);
  hipMemsetAsync(carry, 0, 2 * (size_t)kB * kH * 4, stream);

  const int G = 24 * TC;
  const dim3 grid(32 + 2 * G);
  for (int c = -1; c <= nc + 1; c++) {
    mega<<<grid, 512, 0, stream>>>(c, TC, nc,
        xg0a, xg0b, xg1a, xg1b, h1pa, h1pb,
        x, w_ih0, w_ih1, whp0, whp1,
        b_ih0, b_ih1, b_hh0, b_hh1, carry);
  }

  fc_kernel<<<dim3(kB), dim3(kNOUT), 0, stream>>>(
      carry + (size_t)kB * kH, w_fc, b_fc, out);
}

// Round 6
// 21738.742 us; speedup vs baseline: 2.4672x; 1.5702x over previous
//
#include <hip/hip_runtime.h>
#include <math.h>

typedef unsigned short u16;
typedef __attribute__((ext_vector_type(8))) short s8v;   // 8 x bf16 (4 VGPRs)
typedef __attribute__((ext_vector_type(4))) float f4v;   // MFMA accumulator

constexpr int kB    = 256;
constexpr int kT    = 512;
constexpr int kDIN  = 64;
constexpr int kH    = 512;
constexpr int kG3   = 1536;
constexpr int kNOUT = 128;

__device__ __forceinline__ u16 f2bf(float f) {   // round-to-nearest-even
  union { float f; unsigned u; } v; v.f = f;
  unsigned r = (v.u + 0x7FFFu + ((v.u >> 16) & 1u)) >> 16;
  return (u16)r;
}
__device__ __forceinline__ float fsig(float x) {
  x = fminf(fmaxf(x, -30.f), 30.f);
  float e = __expf(-x);
  return __fdividef(1.f, 1.f + e);
}
__device__ __forceinline__ float ftanh(float x) {
  x = fminf(fmaxf(x, -15.f), 15.f);
  float e = __expf(-2.f * x);
  return __fdividef(1.f - e, 1.f + e);
}

// Group barrier (16 blocks sharing one counter cacheline): release fence +
// monotonic agent-scope counter + acquire spin. target = base + 16*(t+1).
__device__ __forceinline__ void gbar16(unsigned* bar, unsigned target) {
  __threadfence();      // release: stores agent-visible (incl. cross-XCD)
  __syncthreads();      // whole block arrived with stores fenced
  if (threadIdx.x == 0) {
    __hip_atomic_fetch_add(bar, 1u, __ATOMIC_ACQ_REL, __HIP_MEMORY_SCOPE_AGENT);
    int guard = 0;
    while (__hip_atomic_load(bar, __ATOMIC_ACQUIRE, __HIP_MEMORY_SCOPE_AGENT) < target
           && ++guard < (1 << 22)) {
      __builtin_amdgcn_s_sleep(1);
    }
  }
  __syncthreads();
}

// ---------------------------------------------------------------------------
// Pre-swizzle w_hh [1536][512] fp32 -> per-block-slice B-fragment slabs (bf16).
// Slab layout: [jt 16][f 96][lane 64][8],  f = nt*16 + kt,  nt = g*2 + u.
// elem: row = g*512 + jt*32 + u*16 + (lane&15), k = kt*32 + (lane>>4)*8 + i
// ---------------------------------------------------------------------------
__global__ void build_wslab(const float* __restrict__ w, u16* __restrict__ d) {
  int idx  = blockIdx.x * 256 + threadIdx.x;   // 0..98303
  int lane = idx & 63, fg = idx >> 6;          // fg = jt*96 + f
  int jt = fg / 96, f = fg % 96;
  int nt = f >> 4, kt = f & 15;
  int g = nt >> 1, u = nt & 1;
  int row = g * 512 + jt * 32 + u * 16 + (lane & 15);
  int k0  = kt * 32 + (lane >> 4) * 8;
  const float* src = w + (size_t)row * 512 + k0;
  u16* dst = d + ((size_t)fg) * 512 + lane * 8;
#pragma unroll
  for (int i = 0; i < 8; i++) dst[i] = f2bf(src[i]);
}

// ---------------------------------------------------------------------------
// Persistent weight-resident recurrence. REGULAR launch, grid = 256 blocks,
// 256 threads (4 waves). Co-residency is guaranteed by capacity: occupancy
// >= 1 block/CU and grid == CU count, so all blocks are resident.
// Blocks 0..127: layer0 chunk c; 128..255: layer1 chunk c-1.
// Block (bt 0..7, jt 0..15): 32 batches x 32 j. Wave (mt = w>>1, u = w&1):
// 16 batches x 16 j, all 3 gates. Weights: 48 B-fragments/wave in VGPRs.
// h exchange only within the 16 blocks sharing (layer, bt) -> group barrier
// on its own cacheline. hbuf read with agent-scope atomic loads (L1 bypass).
// ---------------------------------------------------------------------------
__global__ __launch_bounds__(256, 1)
void coop_rec(int c, int TC, int nc, unsigned bar_base16, unsigned* bar,
              const float* __restrict__ xg0, const float* __restrict__ xg1,
              const u16* __restrict__ wslab0, const u16* __restrict__ wslab1,
              const float* __restrict__ bhh0, const float* __restrict__ bhh1,
              u16* __restrict__ h1seq, u16* __restrict__ hbuf,
              float* __restrict__ carry) {
  __shared__ u16  stage[32 * 520];   // h_{t-1} [32 batches][512], padded pitch
  __shared__ float hF[32 * 36];      // fp32 state slice [32][32], padded

  const int bid   = blockIdx.x;
  const int layer = bid >> 7;
  const int lb    = bid & 127;
  const int jt    = lb & 15, bt = lb >> 4;
  const int cc    = (layer == 0) ? c : c - 1;
  const bool active = (cc >= 0 && cc < nc);

  unsigned* mybar = bar + (size_t)(layer * 8 + bt) * 64;   // own cacheline

  if (!active) {               // keep the group's counter in lockstep
    for (int t = 0; t < TC; ++t)
      gbar16(mybar, bar_base16 + 16u * (unsigned)(t + 1));
    return;
  }

  const float* xg    = layer ? xg1 : xg0;
  const u16*  wslab  = layer ? wslab1 : wslab0;
  const float* bhh   = layer ? bhh1 : bhh0;
  u16*   myhbuf  = hbuf + (size_t)layer * 2 * kB * kH;
  float* mycarry = carry + (size_t)layer * kB * kH;

  const int tid  = threadIdx.x;
  const int wv   = tid >> 6, lane = tid & 63;
  const int mt   = wv >> 1, u = wv & 1;
  const int b0   = bt * 32;
  const int jl   = lane & 15;
  const int jg   = jt * 32 + u * 16 + jl;        // this lane's output j

  // --- load this wave's 48 B-fragments into registers (once) ---
  s8v bfr[3][16];
  {
    const u16* base = wslab + (size_t)jt * 96 * 512;
#pragma unroll
    for (int g = 0; g < 3; ++g)
#pragma unroll
      for (int kt = 0; kt < 16; ++kt)
        bfr[g][kt] = *(const s8v*)&base[(size_t)((g * 2 + u) * 16 + kt) * 512 + lane * 8];
  }
  const float bh_r = bhh[jg], bh_z = bhh[512 + jg], bh_n = bhh[1024 + jg];

  // --- init fp32 state slice from carry ---
  {
    int row = tid >> 3, c4 = (tid & 7) * 4;
    *(float4*)&hF[row * 36 + c4] =
        *(const float4*)&mycarry[(size_t)(b0 + row) * 512 + jt * 32 + c4];
  }

  for (int t = 0; t < TC; ++t) {
    // --- stage h_{t-1} (bf16): agent-scope atomic dword loads (L1 bypass) ---
    const u16* hsrc = myhbuf + (size_t)(t & 1) * kB * kH;
    {
      int row = tid >> 3, dcol = tid & 7;
      const unsigned* src = (const unsigned*)(hsrc + (size_t)(b0 + row) * 512);
      unsigned* dst = (unsigned*)&stage[row * 520];
#pragma unroll
      for (int k = 0; k < 32; ++k)
        dst[dcol + 8 * k] = __hip_atomic_load(&src[dcol + 8 * k],
                                              __ATOMIC_RELAXED,
                                              __HIP_MEMORY_SCOPE_AGENT);
    }
    __syncthreads();   // stage + (t==0) hF init visible

    // --- xg prefetch: 3 gates x 4 batch-regs per lane ---
    float xv[3][4];
#pragma unroll
    for (int r = 0; r < 4; ++r) {
      int b = b0 + mt * 16 + (lane >> 4) * 4 + r;
      const float* xp = xg + ((size_t)b * TC + t) * kG3;
      xv[0][r] = xp[jg]; xv[1][r] = xp[512 + jg]; xv[2][r] = xp[1024 + jg];
    }

    // --- A-fragments from stage ---
    s8v a[16];
#pragma unroll
    for (int kt = 0; kt < 16; ++kt)
      a[kt] = *(const s8v*)&stage[(mt * 16 + (lane & 15)) * 520 + kt * 32 + (lane >> 4) * 8];

    // --- MFMA: 3 gates x 16 k-tiles ---
    f4v acc[3];
#pragma unroll
    for (int g = 0; g < 3; ++g) acc[g] = (f4v){0.f, 0.f, 0.f, 0.f};
#pragma unroll
    for (int g = 0; g < 3; ++g)
#pragma unroll
      for (int kt = 0; kt < 16; ++kt)
        acc[g] = __builtin_amdgcn_mfma_f32_16x16x32_bf16(a[kt], bfr[g][kt], acc[g], 0, 0, 0);

    // --- gates + state update ---
    u16* hdst = myhbuf + (size_t)((t + 1) & 1) * kB * kH;
#pragma unroll
    for (int r = 0; r < 4; ++r) {
      int ml = mt * 16 + (lane >> 4) * 4 + r;
      int b  = b0 + ml;
      float hp = hF[ml * 36 + u * 16 + jl];
      float rr = fsig(xv[0][r] + acc[0][r] + bh_r);
      float zz = fsig(xv[1][r] + acc[1][r] + bh_z);
      float nn = ftanh(xv[2][r] + rr * (acc[2][r] + bh_n));
      float hn = (1.f - zz) * nn + zz * hp;
      hF[ml * 36 + u * 16 + jl] = hn;
      u16 hb = f2bf(hn);
      hdst[(size_t)b * 512 + jg] = hb;
      if (layer == 0) h1seq[((size_t)b * TC + t) * 512 + jg] = hb;
    }
    gbar16(mybar, bar_base16 + 16u * (unsigned)(t + 1));
  }

  // --- carry writeback (fp32) ---
  {
    int row = tid >> 3, c4 = (tid & 7) * 4;
    *(float4*)&mycarry[(size_t)(b0 + row) * 512 + jt * 32 + c4] =
        *(const float4*)&hF[row * 36 + c4];
  }
}

// ---- GEMM: C[r][1536] = A[r][K] @ W[1536][K]^T + bias (bf16 MFMA) ----
// Row r -> (b = r/TC, t = r%TC); rowptr = A + (b*Abstride + Atoff + t)*K
__device__ void gemm_role(int idx, int TC,
                          const float* __restrict__ Af, const u16* __restrict__ Ab,
                          int Abstride, int Atoff, int K,
                          const float* __restrict__ Bf, const float* __restrict__ bias,
                          float* __restrict__ C, char* smem) {
  u16* As = (u16*)smem;            // [128][40]
  u16* Bs = As + 128 * 40;         // [128][40]
  const int tid = threadIdx.x;
  const int mt = idx / 12, nt = idx % 12;
  const int m0 = mt * 128, n0 = nt * 128;
  const int w = tid >> 6, lane = tid & 63;
  const int wm = w & 1, wn = w >> 1;
  const int ra = tid >> 2, koff = (tid & 3) * 8;

  const int r = m0 + ra;
  const size_t aoff = ((size_t)(r / TC) * Abstride + Atoff + (r % TC)) * K;
  const float* arowF = Af ? Af + aoff : nullptr;
  const u16*  arowB = Ab ? Ab + aoff : nullptr;
  const float* browF = Bf + (size_t)(n0 + ra) * K;

  f4v acc[4][2];
#pragma unroll
  for (int i = 0; i < 4; i++)
#pragma unroll
    for (int jn = 0; jn < 2; jn++) acc[i][jn] = (f4v){0.f, 0.f, 0.f, 0.f};

  for (int k0 = 0; k0 < K; k0 += 32) {
    s8v av, bv;
    if (arowB) {
      av = *(const s8v*)(arowB + k0 + koff);
    } else {
      u16 tmp[8];
      const float* ap = arowF + k0 + koff;
#pragma unroll
      for (int i = 0; i < 8; i++) tmp[i] = f2bf(ap[i]);
      av = *(s8v*)tmp;
    }
    {
      u16 tmp[8];
      const float* bp = browF + k0 + koff;
#pragma unroll
      for (int i = 0; i < 8; i++) tmp[i] = f2bf(bp[i]);
      bv = *(s8v*)tmp;
    }
    __syncthreads();
    *(s8v*)&As[ra * 40 + koff] = av;
    *(s8v*)&Bs[ra * 40 + koff] = bv;
    __syncthreads();
    s8v af[4];
#pragma unroll
    for (int i = 0; i < 4; i++)
      af[i] = *(const s8v*)&As[(wm * 64 + i * 16 + (lane & 15)) * 40 + (lane >> 4) * 8];
#pragma unroll
    for (int jn = 0; jn < 2; jn++) {
      s8v bf = *(const s8v*)&Bs[(wn * 32 + jn * 16 + (lane & 15)) * 40 + (lane >> 4) * 8];
#pragma unroll
      for (int i = 0; i < 4; i++)
        acc[i][jn] = __builtin_amdgcn_mfma_f32_16x16x32_bf16(af[i], bf, acc[i][jn], 0, 0, 0);
    }
  }

#pragma unroll
  for (int jn = 0; jn < 2; jn++) {
    int n = n0 + wn * 32 + jn * 16 + (lane & 15);
    float bv2 = bias[n];
#pragma unroll
    for (int i = 0; i < 4; i++) {
      int mrow = m0 + wm * 64 + i * 16 + (lane >> 4) * 4;
#pragma unroll
      for (int reg = 0; reg < 4; reg++)
        C[(size_t)(mrow + reg) * kG3 + n] = acc[i][jn][reg] + bv2;
    }
  }
}

__global__ __launch_bounds__(512)
void gemm_kernel(int TC, const float* Af, const u16* Ab, int Abstride, int Atoff,
                 int K, const float* Bf, const float* bias, float* C) {
  __shared__ __align__(16) char smem[2 * 128 * 40 * 2];
  gemm_role(blockIdx.x, TC, Af, Ab, Abstride, Atoff, K, Bf, bias, C, smem);
}

// ---------------------------------------------------------------------------
__global__ __launch_bounds__(128)
void fc_kernel(const float* __restrict__ h, const float* __restrict__ wfc,
               const float* __restrict__ bfc, float* __restrict__ out) {
  const int b = blockIdx.x;
  const int n = threadIdx.x;
  const float* hrow = h + (size_t)b * kH;
  const float* wrow = wfc + (size_t)n * kH;
  float acc = 0.f;
#pragma unroll 4
  for (int k = 0; k < kH; k += 4) {
    const float4 hv = *(const float4*)&hrow[k];
    const float4 wv = *(const float4*)&wrow[k];
    acc = fmaf(hv.x, wv.x, acc); acc = fmaf(hv.y, wv.y, acc);
    acc = fmaf(hv.z, wv.z, acc); acc = fmaf(hv.w, wv.w, acc);
  }
  out[(size_t)b * kNOUT + n] = acc + bfc[n];
}

// ---------------------------------------------------------------------------
extern "C" void kernel_launch(void* const* d_in, const int* in_sizes, int n_in,
                              void* d_out, int out_size, void* d_ws, size_t ws_size,
                              hipStream_t stream) {
  const float* x     = (const float*)d_in[0];
  const float* w_ih0 = (const float*)d_in[1];
  const float* w_hh0 = (const float*)d_in[2];
  const float* b_ih0 = (const float*)d_in[3];
  const float* b_hh0 = (const float*)d_in[4];
  const float* w_ih1 = (const float*)d_in[5];
  const float* w_hh1 = (const float*)d_in[6];
  const float* b_ih1 = (const float*)d_in[7];
  const float* b_hh1 = (const float*)d_in[8];
  const float* w_fc  = (const float*)d_in[9];
  const float* b_fc  = (const float*)d_in[10];
  float* out = (float*)d_out;

  // workspace sizing (TC adaptive; TC=64 needs ~223 MB)
  auto need = [](int tc) -> size_t {
    size_t s = 0;
    s += 2 * (size_t)kB * tc * kG3 * 4;   // xg0 + xg1 fp32
    s += (size_t)kB * tc * kH * 2;        // h1seq bf16
    s += 2 * (size_t)kG3 * kH * 2;        // wslab x2
    s += 4 * (size_t)kB * kH * 2;         // hbuf [2 layers][2 parity] bf16
    s += 2 * (size_t)kB * kH * 4;         // carry fp32 x2
    s += 32768;
    return s;
  };
  int TC = 64;
  while (TC > 2 && need(TC) > ws_size) TC >>= 1;
  const int nc = kT / TC;

  char* p = (char*)d_ws;
  auto carve = [&](size_t bytes) {
    char* r = p; p += (bytes + 255) & ~(size_t)255; return r;
  };
  float* xg0   = (float*)carve((size_t)kB * TC * kG3 * 4);
  float* xg1   = (float*)carve((size_t)kB * TC * kG3 * 4);
  u16* h1seq   = (u16*)carve((size_t)kB * TC * kH * 2);
  u16* wslab0  = (u16*)carve((size_t)kG3 * kH * 2);
  u16* wslab1  = (u16*)carve((size_t)kG3 * kH * 2);
  u16* hbuf    = (u16*)carve(4 * (size_t)kB * kH * 2);
  float* carry = (float*)carve(2 * (size_t)kB * kH * 4);
  unsigned* bar = (unsigned*)carve(32 * 64 * sizeof(unsigned));  // 32 cachelines

  // prologue: weight swizzle + zero h-state (hbuf + carries) + barrier counters
  build_wslab<<<384, 256, 0, stream>>>(w_hh0, wslab0);
  build_wslab<<<384, 256, 0, stream>>>(w_hh1, wslab1);
  hipMemsetAsync(hbuf, 0, 4 * (size_t)kB * kH * 2 + 2 * (size_t)kB * kH * 4, stream);
  hipMemsetAsync(bar, 0, 32 * 64 * sizeof(unsigned), stream);

  const dim3 ggrid(2 * TC * 12);   // (256*TC/128) m-tiles x 12 n-tiles

  for (int c = 0; c <= nc; ++c) {
    if (c < nc) {
      // proj0(c): xg0 = x(chunk c) @ w_ih0^T + b_ih0
      gemm_kernel<<<ggrid, 512, 0, stream>>>(TC, x, nullptr, kT, c * TC, kDIN,
                                             w_ih0, b_ih0, xg0);
    }
    // persistent recurrence: rec0(c) blocks 0..127, rec1(c-1) blocks 128..255
    {
      unsigned base16 = (unsigned)c * 16u * (unsigned)TC;
      coop_rec<<<dim3(256), dim3(256), 0, stream>>>(
          c, TC, nc, base16, bar, xg0, xg1, wslab0, wslab1,
          b_hh0, b_hh1, h1seq, hbuf, carry);
    }
    if (c < nc) {
      // proj1(c): xg1 = h1seq(c) @ w_ih1^T + b_ih1
      gemm_kernel<<<ggrid, 512, 0, stream>>>(TC, nullptr, h1seq, TC, 0, kH,
                                             w_ih1, b_ih1, xg1);
    }
  }

  // final FC on layer-1 carry (fp32)
  fc_kernel<<<dim3(kB), dim3(kNOUT), 0, stream>>>(
      carry + (size_t)kB * kH, w_fc, b_fc, out);
}